// Round 10
// baseline (602.990 us; speedup 1.0000x reference)
//
#include <hip/hip_runtime.h>
#include <hip/hip_bf16.h>

#define NN 100000     // nodes
#define NE 400000     // edges
#define DD 128        // feature dim
#define NG 4096       // graphs
#define NL 5          // layers
#define NF 11         // in features
#define GROWS 100096  // g rows rounded up to 128 (782 blocks * 128)

typedef __attribute__((ext_vector_type(8))) __bf16 bf16x8;
typedef __attribute__((ext_vector_type(4))) float f32x4;

// ---------------- preprocessing ----------------

__global__ void deg_kernel(const int* __restrict__ ei, int* __restrict__ deg) {
    int e = blockIdx.x * 256 + threadIdx.x;
    if (e < NE) atomicAdd(&deg[ei[NE + e]], 1);
}

// block scans 1024 elements (4 per thread), writes per-block total
__global__ void scan1_kernel(const int* __restrict__ deg, int* __restrict__ off,
                             int* __restrict__ bsums) {
    __shared__ int lds[256];
    int tid = threadIdx.x, b = blockIdx.x;
    int base = b * 1024 + tid * 4;
    int v[4];
#pragma unroll
    for (int q = 0; q < 4; ++q) {
        int i = base + q;
        v[q] = (i < NN) ? deg[i] : 0;
    }
    int s = v[0] + v[1] + v[2] + v[3];
    lds[tid] = s;
    __syncthreads();
    for (int o = 1; o < 256; o <<= 1) {
        int t2 = (tid >= o) ? lds[tid - o] : 0;
        __syncthreads();
        lds[tid] += t2;
        __syncthreads();
    }
    int p = lds[tid] - s;  // exclusive prefix for this thread
#pragma unroll
    for (int q = 0; q < 4; ++q) {
        int i = base + q;
        if (i < NN) off[i] = p;
        p += v[q];
    }
    if (tid == 255) bsums[b] = lds[255];
}

__global__ void scan2_kernel(int* __restrict__ bsums, int nb) {
    __shared__ int lds[128];
    int tid = threadIdx.x;
    int v = (tid < nb) ? bsums[tid] : 0;
    lds[tid] = v;
    __syncthreads();
    for (int o = 1; o < 128; o <<= 1) {
        int t2 = (tid >= o) ? lds[tid - o] : 0;
        __syncthreads();
        lds[tid] += t2;
        __syncthreads();
    }
    if (tid < nb) bsums[tid] = lds[tid] - v;  // exclusive
}

__global__ void finish_kernel(int* __restrict__ off, const int* __restrict__ bsums,
                              const int* __restrict__ deg, float* __restrict__ dinv) {
    int i = blockIdx.x * 256 + threadIdx.x;
    if (i == 0) off[NN] = NE;
    if (i < NN) {
        off[i] += bsums[i >> 10];
        dinv[i] = rsqrtf((float)deg[i] + 2.0f);
    }
}

// packed CSR record: .x = src index, .y = bitcast(norm)
__global__ void fill_kernel(const int* __restrict__ ei, const int* __restrict__ off,
                            int* __restrict__ cursor, int2* __restrict__ csr,
                            const float* __restrict__ dinv) {
    int e = blockIdx.x * 256 + threadIdx.x;
    if (e >= NE) return;
    int s = ei[e];
    int d = ei[NE + e];
    int pos = off[d] + atomicAdd(&cursor[d], 1);
    csr[pos] = make_int2(s, __float_as_int(dinv[s] * dinv[d]));
}

// ---------------- W pre-pack: A-fragment-order bf16 hi/lo (W^T as MFMA A operand) ------
// Layout per layer: [ft(8)][kc(4)][lane(64)][i(8)]; slot (lane,i) holds
// A[row = ft*16 + (lane&15)][k = kc*32 + (lane>>4)*8 + i] = W[k][f].

__global__ void wpack_kernel(const float* __restrict__ Wg, unsigned short* __restrict__ whi,
                             unsigned short* __restrict__ wlo) {
    int t = blockIdx.x * 256 + threadIdx.x;  // < NL*16384
    int l = t >> 14, r = t & 16383;
    int k = r >> 7, n = r & 127;
    float w = Wg[(size_t)l * 16384 + k * 128 + n];
    __bf16 hb = (__bf16)w;
    float lo = w - (float)hb;
    __bf16 lb = (__bf16)lo;
    int ft = n >> 4, kc = k >> 5, lane = (((k >> 3) & 3) << 4) | (n & 15), i = k & 7;
    size_t idx = (size_t)l * 16384 + (((ft * 4 + kc) * 64 + lane) * 8 + i);
    whi[idx] = __builtin_bit_cast(unsigned short, hb);
    wlo[idx] = __builtin_bit_cast(unsigned short, lb);
}

// ---------------- expansion: h = log(x+1) @ We + be  (logs computed in-block) ----------

__global__ __launch_bounds__(256) void expand_kernel(const float* __restrict__ x,
                                                     const float* __restrict__ We,
                                                     const float* __restrict__ be,
                                                     float* __restrict__ h) {
    __shared__ float ls[2 * NF];
    const int tid = threadIdx.x;
    const int node0 = blockIdx.x * 2;
    if (tid < 2 * NF) ls[tid] = __logf(x[(size_t)node0 * NF + tid] + 1.0f);
    __syncthreads();
    const int row = tid >> 7, j = tid & 127;
    float acc = be[j];
#pragma unroll
    for (int f = 0; f < NF; ++f) {
        acc = fmaf(ls[row * NF + f], We[f * DD + j], acc);
    }
    h[(size_t)(node0 + row) * DD + j] = acc;
}

// ---------------- aggregation: g = self_norm*h + sum_e enorm*h[src] ----------------
// 32 lanes per node (float4 per lane), 8 nodes per 256-block.
// PREDICATED 4-unroll: always 4 independent 16B gathers in flight
// (clamped idx -> dup loads coalesce/L1-hit; zeroed tail weights). No serial remainder.

__global__ __launch_bounds__(256) void agg_kernel(const float* __restrict__ h,
                                                  float* __restrict__ g,
                                                  const int* __restrict__ off,
                                                  const int2* __restrict__ csr,
                                                  const float* __restrict__ dinv) {
    const int tid = threadIdx.x;
    const int node = blockIdx.x * 8 + (tid >> 5);
    const int jj = tid & 31;
    const float4* __restrict__ h4 = (const float4*)h;

    float di = dinv[node];
    float sn = 2.0f * di * di;
    float4 hv = h4[(size_t)node * 32 + jj];
    float4 acc = make_float4(sn * hv.x, sn * hv.y, sn * hv.z, sn * hv.w);

    const int e0 = off[node];
    const int e1 = off[node + 1];
#pragma unroll 1
    for (int e = e0; e < e1; e += 4) {
        const int eL = e1 - 1;
        int2 r0 = csr[e];
        int2 r1 = csr[min(e + 1, eL)];
        int2 r2 = csr[min(e + 2, eL)];
        int2 r3 = csr[min(e + 3, eL)];
        float4 v0 = h4[(size_t)r0.x * 32 + jj];
        float4 v1 = h4[(size_t)r1.x * 32 + jj];
        float4 v2 = h4[(size_t)r2.x * 32 + jj];
        float4 v3 = h4[(size_t)r3.x * 32 + jj];
        float w0 = __int_as_float(r0.y);
        float w1 = (e + 1 < e1) ? __int_as_float(r1.y) : 0.f;
        float w2 = (e + 2 < e1) ? __int_as_float(r2.y) : 0.f;
        float w3 = (e + 3 < e1) ? __int_as_float(r3.y) : 0.f;
        acc.x = fmaf(w0, v0.x, acc.x); acc.y = fmaf(w0, v0.y, acc.y);
        acc.z = fmaf(w0, v0.z, acc.z); acc.w = fmaf(w0, v0.w, acc.w);
        acc.x = fmaf(w1, v1.x, acc.x); acc.y = fmaf(w1, v1.y, acc.y);
        acc.z = fmaf(w1, v1.z, acc.z); acc.w = fmaf(w1, v1.w, acc.w);
        acc.x = fmaf(w2, v2.x, acc.x); acc.y = fmaf(w2, v2.y, acc.y);
        acc.z = fmaf(w2, v2.z, acc.z); acc.w = fmaf(w2, v2.w, acc.w);
        acc.x = fmaf(w3, v3.x, acc.x); acc.y = fmaf(w3, v3.y, acc.y);
        acc.z = fmaf(w3, v3.z, acc.z); acc.w = fmaf(w3, v3.w, acc.w);
    }
    ((float4*)g)[(size_t)node * 32 + jj] = acc;
}

// ---------------- MFMA GEMM v3 (operand-swapped, 32 nodes/wave): D = W^T · g^T --------
// Each W fragment load feeds TWO node-subtiles (nt=0,1) -> 2x MFMA per W byte.
// Wave = 32 nodes x 128 features; block = 4 waves = 128 nodes. No LDS, no barriers.
// 3-term split: Whi*ghi + Wlo*ghi + Whi*glo (fp32 accum).
// C/D fragment: col=lane&15 -> node, row=(lane>>4)*4+j -> 4 consecutive features.

__global__ __launch_bounds__(256) void mfma_gemm(const float* __restrict__ g,
                                                 float* __restrict__ h,
                                                 const unsigned short* __restrict__ whi,
                                                 const unsigned short* __restrict__ wlo,
                                                 const float* __restrict__ b) {
    const int lane = threadIdx.x & 63;
    const int wv = threadIdx.x >> 6;
    const int nbase = blockIdx.x * 128 + wv * 32 + (lane & 15);
    const int kg = lane >> 4;  // 0..3

    // load + split g for both node-subtiles (16 independent dwordx4 in flight)
    bf16x8 gh[2][4], gl[2][4];
#pragma unroll
    for (int nt = 0; nt < 2; ++nt) {
        const float* gp = g + (size_t)(nbase + nt * 16) * DD + kg * 8;
#pragma unroll
        for (int kc = 0; kc < 4; ++kc) {
            float4 f0 = *(const float4*)(gp + kc * 32);
            float4 f1 = *(const float4*)(gp + kc * 32 + 4);
            float t[8] = {f0.x, f0.y, f0.z, f0.w, f1.x, f1.y, f1.z, f1.w};
#pragma unroll
            for (int i = 0; i < 8; ++i) {
                __bf16 hi = (__bf16)t[i];
                float lo = t[i] - (float)hi;
                gh[nt][kc][i] = hi;
                gl[nt][kc][i] = (__bf16)lo;
            }
        }
    }

    f32x4 c[2][8];
#pragma unroll
    for (int nt = 0; nt < 2; ++nt)
#pragma unroll
        for (int ft = 0; ft < 8; ++ft) c[nt][ft] = (f32x4){0.f, 0.f, 0.f, 0.f};

#pragma unroll
    for (int kc = 0; kc < 4; ++kc) {
#pragma unroll
        for (int ft = 0; ft < 8; ++ft) {
            size_t boff = (size_t)(((ft * 4 + kc) * 64 + lane) * 8);
            bf16x8 wh = *(const bf16x8*)(whi + boff);
            bf16x8 wl = *(const bf16x8*)(wlo + boff);
#pragma unroll
            for (int nt = 0; nt < 2; ++nt) {
                c[nt][ft] = __builtin_amdgcn_mfma_f32_16x16x32_bf16(wh, gh[nt][kc], c[nt][ft], 0, 0, 0);
                c[nt][ft] = __builtin_amdgcn_mfma_f32_16x16x32_bf16(wl, gh[nt][kc], c[nt][ft], 0, 0, 0);
                c[nt][ft] = __builtin_amdgcn_mfma_f32_16x16x32_bf16(wh, gl[nt][kc], c[nt][ft], 0, 0, 0);
            }
        }
    }

    // epilogue: lane holds features f = ft*16 + kg*4 + j (j=0..3) of node nbase+nt*16
    const int f0 = kg * 4;
#pragma unroll
    for (int nt = 0; nt < 2; ++nt) {
        const int node = nbase + nt * 16;
        if (node < NN) {
#pragma unroll
            for (int ft = 0; ft < 8; ++ft) {
                size_t o = (size_t)node * DD + ft * 16 + f0;
                float4 hv = *(const float4*)(h + o);
                float4 bv = *(const float4*)(b + ft * 16 + f0);
                hv.x += fmaxf(c[nt][ft][0] + bv.x, 0.f);
                hv.y += fmaxf(c[nt][ft][1] + bv.y, 0.f);
                hv.z += fmaxf(c[nt][ft][2] + bv.z, 0.f);
                hv.w += fmaxf(c[nt][ft][3] + bv.w, 0.f);
                *(float4*)(h + o) = hv;
            }
        }
    }
}

// ---------------- pool: out[batch[i]] += h[i]  (batch sorted) ----------------

__global__ void pool_kernel(const float* __restrict__ h, const int* __restrict__ batch,
                            float* __restrict__ out) {
    int j = threadIdx.x;  // 128
    int n0 = blockIdx.x * 64;
    float acc = 0.f;
    int prev = -1;
    for (int n = 0; n < 64; ++n) {
        int i = n0 + n;
        if (i >= NN) break;
        int bi = batch[i];
        if (bi != prev) {
            if (prev >= 0) atomicAdd(&out[(size_t)prev * DD + j], acc);
            acc = 0.f;
            prev = bi;
        }
        acc += h[(size_t)i * DD + j];
    }
    if (prev >= 0) atomicAdd(&out[(size_t)prev * DD + j], acc);
}

// ---------------- launch ----------------

static inline size_t align_up(size_t x, size_t a) { return (x + a - 1) & ~(a - 1); }

extern "C" void kernel_launch(void* const* d_in, const int* in_sizes, int n_in,
                              void* d_out, int out_size, void* d_ws, size_t ws_size,
                              hipStream_t stream) {
    const float* x   = (const float*)d_in[0];
    const int*   ei  = (const int*)d_in[1];
    const int*   bat = (const int*)d_in[2];
    const float* We  = (const float*)d_in[4];
    const float* be  = (const float*)d_in[5];
    const float* Wg  = (const float*)d_in[6];
    const float* bg  = (const float*)d_in[7];
    float* out = (float*)d_out;

    // workspace carve-up
    char* p = (char*)d_ws;
    size_t o = 0;
    float* h = (float*)(p + o);       o = align_up(o + (size_t)NN * DD * 4, 512);
    float* g = (float*)(p + o);       o = align_up(o + (size_t)GROWS * DD * 4, 512);
    float* dinv = (float*)(p + o);    o = align_up(o + (size_t)NN * 4, 512);
    int* deg = (int*)(p + o);         o = align_up(o + (size_t)NN * 4, 512);
    int* cursor = (int*)(p + o);      o = align_up(o + (size_t)NN * 4, 512);
    int* off = (int*)(p + o);         o = align_up(o + (size_t)(NN + 1) * 4, 512);
    int* bsums = (int*)(p + o);       o = align_up(o + 512, 512);
    int2* csr = (int2*)(p + o);       o = align_up(o + (size_t)NE * 8, 512);
    unsigned short* whi = (unsigned short*)(p + o); o = align_up(o + (size_t)NL * 16384 * 2, 512);
    unsigned short* wlo = (unsigned short*)(p + o); o = align_up(o + (size_t)NL * 16384 * 2, 512);
    (void)ws_size; (void)in_sizes; (void)n_in; (void)out_size;

    const int GRID_E = (NE + 255) / 256;          // 1563
    const int GRID_SCAN1 = (NN + 1023) / 1024;    // 98
    const int GRID_N256 = (NN + 255) / 256;       // 391
    const int GRID_EXP = NN / 2;                  // 50000
    const int GRID_AGG = NN / 8;                  // 12500
    const int GRID_GEMM = GROWS / 128;            // 782
    const int GRID_POOL = (NN + 63) / 64;         // 1563
    const int GRID_WPACK = NL * 16384 / 256;      // 320

    // zero deg + cursor (ws is poisoned 0xAA each call)
    hipMemsetAsync(deg, 0, (size_t)NN * 4, stream);
    hipMemsetAsync(cursor, 0, (size_t)NN * 4, stream);
    hipMemsetAsync(out, 0, (size_t)NG * DD * 4, stream);

    deg_kernel<<<GRID_E, 256, 0, stream>>>(ei, deg);
    scan1_kernel<<<GRID_SCAN1, 256, 0, stream>>>(deg, off, bsums);
    scan2_kernel<<<1, 128, 0, stream>>>(bsums, GRID_SCAN1);
    finish_kernel<<<GRID_N256, 256, 0, stream>>>(off, bsums, deg, dinv);
    fill_kernel<<<GRID_E, 256, 0, stream>>>(ei, off, cursor, csr, dinv);
    wpack_kernel<<<GRID_WPACK, 256, 0, stream>>>(Wg, whi, wlo);

    expand_kernel<<<GRID_EXP, 256, 0, stream>>>(x, We, be, h);

    for (int l = 0; l < NL; ++l) {
        agg_kernel<<<GRID_AGG, 256, 0, stream>>>(h, g, off, csr, dinv);
        mfma_gemm<<<GRID_GEMM, 256, 0, stream>>>(g, h,
                                                 whi + (size_t)l * 16384,
                                                 wlo + (size_t)l * 16384,
                                                 bg + (size_t)l * DD);
    }

    pool_kernel<<<GRID_POOL, 128, 0, stream>>>(h, bat, out);
}

// Round 11
// 594.835 us; speedup vs baseline: 1.0137x; 1.0137x over previous
//
#include <hip/hip_runtime.h>
#include <hip/hip_bf16.h>

#define NN 100000     // nodes
#define NE 400000     // edges
#define DD 128        // feature dim
#define NG 4096       // graphs
#define NL 5          // layers
#define NF 11         // in features
#define GROWS 100096  // g rows rounded up to 128 (782 blocks * 128)

typedef __attribute__((ext_vector_type(8))) __bf16 bf16x8;
typedef __attribute__((ext_vector_type(4))) float f32x4;

// ---------------- preprocessing ----------------

__global__ void deg_kernel(const int* __restrict__ ei, int* __restrict__ deg) {
    int e = blockIdx.x * 256 + threadIdx.x;
    if (e < NE) atomicAdd(&deg[ei[NE + e]], 1);
}

// block scans 1024 elements (4 per thread), writes per-block total
__global__ void scan1_kernel(const int* __restrict__ deg, int* __restrict__ off,
                             int* __restrict__ bsums) {
    __shared__ int lds[256];
    int tid = threadIdx.x, b = blockIdx.x;
    int base = b * 1024 + tid * 4;
    int v[4];
#pragma unroll
    for (int q = 0; q < 4; ++q) {
        int i = base + q;
        v[q] = (i < NN) ? deg[i] : 0;
    }
    int s = v[0] + v[1] + v[2] + v[3];
    lds[tid] = s;
    __syncthreads();
    for (int o = 1; o < 256; o <<= 1) {
        int t2 = (tid >= o) ? lds[tid - o] : 0;
        __syncthreads();
        lds[tid] += t2;
        __syncthreads();
    }
    int p = lds[tid] - s;  // exclusive prefix for this thread
#pragma unroll
    for (int q = 0; q < 4; ++q) {
        int i = base + q;
        if (i < NN) off[i] = p;
        p += v[q];
    }
    if (tid == 255) bsums[b] = lds[255];
}

__global__ void scan2_kernel(int* __restrict__ bsums, int nb) {
    __shared__ int lds[128];
    int tid = threadIdx.x;
    int v = (tid < nb) ? bsums[tid] : 0;
    lds[tid] = v;
    __syncthreads();
    for (int o = 1; o < 128; o <<= 1) {
        int t2 = (tid >= o) ? lds[tid - o] : 0;
        __syncthreads();
        lds[tid] += t2;
        __syncthreads();
    }
    if (tid < nb) bsums[tid] = lds[tid] - v;  // exclusive
}

__global__ void finish_kernel(int* __restrict__ off, const int* __restrict__ bsums,
                              const int* __restrict__ deg, float* __restrict__ dinv) {
    int i = blockIdx.x * 256 + threadIdx.x;
    if (i == 0) off[NN] = NE;
    if (i < NN) {
        off[i] += bsums[i >> 10];
        dinv[i] = rsqrtf((float)deg[i] + 2.0f);
    }
}

// packed CSR record: .x = src index, .y = bitcast(norm)
__global__ void fill_kernel(const int* __restrict__ ei, const int* __restrict__ off,
                            int* __restrict__ cursor, int2* __restrict__ csr,
                            const float* __restrict__ dinv) {
    int e = blockIdx.x * 256 + threadIdx.x;
    if (e >= NE) return;
    int s = ei[e];
    int d = ei[NE + e];
    int pos = off[d] + atomicAdd(&cursor[d], 1);
    csr[pos] = make_int2(s, __float_as_int(dinv[s] * dinv[d]));
}

// ---------------- W pre-pack: A-fragment-order bf16 hi/lo (W^T as MFMA A operand) ------
// Layout per layer: [ft(8)][kc(4)][lane(64)][i(8)]; slot (lane,i) holds
// A[row = ft*16 + (lane&15)][k = kc*32 + (lane>>4)*8 + i] = W[k][f].

__global__ void wpack_kernel(const float* __restrict__ Wg, unsigned short* __restrict__ whi,
                             unsigned short* __restrict__ wlo) {
    int t = blockIdx.x * 256 + threadIdx.x;  // < NL*16384
    int l = t >> 14, r = t & 16383;
    int k = r >> 7, n = r & 127;
    float w = Wg[(size_t)l * 16384 + k * 128 + n];
    __bf16 hb = (__bf16)w;
    float lo = w - (float)hb;
    __bf16 lb = (__bf16)lo;
    int ft = n >> 4, kc = k >> 5, lane = (((k >> 3) & 3) << 4) | (n & 15), i = k & 7;
    size_t idx = (size_t)l * 16384 + (((ft * 4 + kc) * 64 + lane) * 8 + i);
    whi[idx] = __builtin_bit_cast(unsigned short, hb);
    wlo[idx] = __builtin_bit_cast(unsigned short, lb);
}

// ---------------- expansion: h = log(x+1) @ We + be  (logs computed in-block) ----------

__global__ __launch_bounds__(256) void expand_kernel(const float* __restrict__ x,
                                                     const float* __restrict__ We,
                                                     const float* __restrict__ be,
                                                     float* __restrict__ h) {
    __shared__ float ls[2 * NF];
    const int tid = threadIdx.x;
    const int node0 = blockIdx.x * 2;
    if (tid < 2 * NF) ls[tid] = __logf(x[(size_t)node0 * NF + tid] + 1.0f);
    __syncthreads();
    const int row = tid >> 7, j = tid & 127;
    float acc = be[j];
#pragma unroll
    for (int f = 0; f < NF; ++f) {
        acc = fmaf(ls[row * NF + f], We[f * DD + j], acc);
    }
    h[(size_t)(node0 + row) * DD + j] = acc;
}

// ---------------- aggregation: g = self_norm*h + sum_e enorm*h[src] ----------------
// 32 lanes per node (float4 per lane), 8 nodes per 256-block.
// PREDICATED 4-unroll: always 4 independent 16B gathers in flight
// (clamped idx -> dup loads coalesce/L1-hit; zeroed tail weights). No serial remainder.

__global__ __launch_bounds__(256) void agg_kernel(const float* __restrict__ h,
                                                  float* __restrict__ g,
                                                  const int* __restrict__ off,
                                                  const int2* __restrict__ csr,
                                                  const float* __restrict__ dinv) {
    const int tid = threadIdx.x;
    const int node = blockIdx.x * 8 + (tid >> 5);
    const int jj = tid & 31;
    const float4* __restrict__ h4 = (const float4*)h;

    float di = dinv[node];
    float sn = 2.0f * di * di;
    float4 hv = h4[(size_t)node * 32 + jj];
    float4 acc = make_float4(sn * hv.x, sn * hv.y, sn * hv.z, sn * hv.w);

    const int e0 = off[node];
    const int e1 = off[node + 1];
#pragma unroll 1
    for (int e = e0; e < e1; e += 4) {
        const int eL = e1 - 1;
        int2 r0 = csr[e];
        int2 r1 = csr[min(e + 1, eL)];
        int2 r2 = csr[min(e + 2, eL)];
        int2 r3 = csr[min(e + 3, eL)];
        float4 v0 = h4[(size_t)r0.x * 32 + jj];
        float4 v1 = h4[(size_t)r1.x * 32 + jj];
        float4 v2 = h4[(size_t)r2.x * 32 + jj];
        float4 v3 = h4[(size_t)r3.x * 32 + jj];
        float w0 = __int_as_float(r0.y);
        float w1 = (e + 1 < e1) ? __int_as_float(r1.y) : 0.f;
        float w2 = (e + 2 < e1) ? __int_as_float(r2.y) : 0.f;
        float w3 = (e + 3 < e1) ? __int_as_float(r3.y) : 0.f;
        acc.x = fmaf(w0, v0.x, acc.x); acc.y = fmaf(w0, v0.y, acc.y);
        acc.z = fmaf(w0, v0.z, acc.z); acc.w = fmaf(w0, v0.w, acc.w);
        acc.x = fmaf(w1, v1.x, acc.x); acc.y = fmaf(w1, v1.y, acc.y);
        acc.z = fmaf(w1, v1.z, acc.z); acc.w = fmaf(w1, v1.w, acc.w);
        acc.x = fmaf(w2, v2.x, acc.x); acc.y = fmaf(w2, v2.y, acc.y);
        acc.z = fmaf(w2, v2.z, acc.z); acc.w = fmaf(w2, v2.w, acc.w);
        acc.x = fmaf(w3, v3.x, acc.x); acc.y = fmaf(w3, v3.y, acc.y);
        acc.z = fmaf(w3, v3.z, acc.z); acc.w = fmaf(w3, v3.w, acc.w);
    }
    ((float4*)g)[(size_t)node * 32 + jj] = acc;
}

// ---------------- MFMA GEMM v4 (LDS-staged g): D = W^T · g^T ----------------
// Block = 128 nodes, 4 waves (32 nodes each, 2 nt-subtiles). g tile staged into
// LDS with one coalesced pass (8 full rows = 4KB/instr), fragments read via
// ds_read_b128 (bank-balanced). One barrier. Epilogue: float4 RMW of h.
// 3-term split: Whi*ghi + Wlo*ghi + Whi*glo (fp32 accum).
// C/D fragment: col=lane&15 -> node, row=(lane>>4)*4+j -> 4 consecutive features.

__global__ __launch_bounds__(256) void mfma_gemm(const float* __restrict__ g,
                                                 float* __restrict__ h,
                                                 const unsigned short* __restrict__ whi,
                                                 const unsigned short* __restrict__ wlo,
                                                 const float* __restrict__ b) {
    __shared__ float gs[128 * 132];
    const int tid = threadIdx.x;
    const int lane = tid & 63;
    const int wv = tid >> 6;
    const int node0 = blockIdx.x * 128;

    // ---- stage g tile, coalesced ----
#pragma unroll
    for (int it = 0; it < 16; ++it) {
        int idx = it * 1024 + tid * 4;
        int r = idx >> 7, c = idx & 127;
        float4 v = *(const float4*)(g + (size_t)(node0 + r) * DD + c);
        *(float4*)&gs[r * 132 + c] = v;
    }
    __syncthreads();

    const int kg = lane >> 4;   // 0..3
    const int nl = lane & 15;

    // ---- fragments from LDS + hi/lo split ----
    bf16x8 gh[2][4], gl[2][4];
#pragma unroll
    for (int nt = 0; nt < 2; ++nt) {
        const int lrow = wv * 32 + nt * 16 + nl;
#pragma unroll
        for (int kc = 0; kc < 4; ++kc) {
            const float* lp = &gs[lrow * 132 + kc * 32 + kg * 8];
            float4 f0 = *(const float4*)lp;
            float4 f1 = *(const float4*)(lp + 4);
            float t[8] = {f0.x, f0.y, f0.z, f0.w, f1.x, f1.y, f1.z, f1.w};
#pragma unroll
            for (int i = 0; i < 8; ++i) {
                __bf16 hi = (__bf16)t[i];
                float lo = t[i] - (float)hi;
                gh[nt][kc][i] = hi;
                gl[nt][kc][i] = (__bf16)lo;
            }
        }
    }

    f32x4 c[2][8];
#pragma unroll
    for (int nt = 0; nt < 2; ++nt)
#pragma unroll
        for (int ft = 0; ft < 8; ++ft) c[nt][ft] = (f32x4){0.f, 0.f, 0.f, 0.f};

#pragma unroll
    for (int kc = 0; kc < 4; ++kc) {
#pragma unroll
        for (int ft = 0; ft < 8; ++ft) {
            size_t boff = (size_t)(((ft * 4 + kc) * 64 + lane) * 8);
            bf16x8 wh = *(const bf16x8*)(whi + boff);
            bf16x8 wl = *(const bf16x8*)(wlo + boff);
#pragma unroll
            for (int nt = 0; nt < 2; ++nt) {
                c[nt][ft] = __builtin_amdgcn_mfma_f32_16x16x32_bf16(wh, gh[nt][kc], c[nt][ft], 0, 0, 0);
                c[nt][ft] = __builtin_amdgcn_mfma_f32_16x16x32_bf16(wl, gh[nt][kc], c[nt][ft], 0, 0, 0);
                c[nt][ft] = __builtin_amdgcn_mfma_f32_16x16x32_bf16(wh, gl[nt][kc], c[nt][ft], 0, 0, 0);
            }
        }
    }

    // ---- epilogue: lane holds features f = ft*16 + kg*4 + j (j=0..3) of its node ----
    const int f0 = kg * 4;
#pragma unroll
    for (int nt = 0; nt < 2; ++nt) {
        const int node = node0 + wv * 32 + nt * 16 + nl;
        if (node < NN) {
#pragma unroll
            for (int ft = 0; ft < 8; ++ft) {
                size_t o = (size_t)node * DD + ft * 16 + f0;
                float4 hv = *(const float4*)(h + o);
                float4 bv = *(const float4*)(b + ft * 16 + f0);
                hv.x += fmaxf(c[nt][ft][0] + bv.x, 0.f);
                hv.y += fmaxf(c[nt][ft][1] + bv.y, 0.f);
                hv.z += fmaxf(c[nt][ft][2] + bv.z, 0.f);
                hv.w += fmaxf(c[nt][ft][3] + bv.w, 0.f);
                *(float4*)(h + o) = hv;
            }
        }
    }
}

// ---------------- pool: out[batch[i]] += h[i]  (batch sorted) ----------------

__global__ void pool_kernel(const float* __restrict__ h, const int* __restrict__ batch,
                            float* __restrict__ out) {
    int j = threadIdx.x;  // 128
    int n0 = blockIdx.x * 64;
    float acc = 0.f;
    int prev = -1;
    for (int n = 0; n < 64; ++n) {
        int i = n0 + n;
        if (i >= NN) break;
        int bi = batch[i];
        if (bi != prev) {
            if (prev >= 0) atomicAdd(&out[(size_t)prev * DD + j], acc);
            acc = 0.f;
            prev = bi;
        }
        acc += h[(size_t)i * DD + j];
    }
    if (prev >= 0) atomicAdd(&out[(size_t)prev * DD + j], acc);
}

// ---------------- launch ----------------

static inline size_t align_up(size_t x, size_t a) { return (x + a - 1) & ~(a - 1); }

extern "C" void kernel_launch(void* const* d_in, const int* in_sizes, int n_in,
                              void* d_out, int out_size, void* d_ws, size_t ws_size,
                              hipStream_t stream) {
    const float* x   = (const float*)d_in[0];
    const int*   ei  = (const int*)d_in[1];
    const int*   bat = (const int*)d_in[2];
    const float* We  = (const float*)d_in[4];
    const float* be  = (const float*)d_in[5];
    const float* Wg  = (const float*)d_in[6];
    const float* bg  = (const float*)d_in[7];
    float* out = (float*)d_out;

    // workspace carve-up
    char* p = (char*)d_ws;
    size_t o = 0;
    float* h = (float*)(p + o);       o = align_up(o + (size_t)NN * DD * 4, 512);
    float* g = (float*)(p + o);       o = align_up(o + (size_t)GROWS * DD * 4, 512);
    float* dinv = (float*)(p + o);    o = align_up(o + (size_t)NN * 4, 512);
    int* deg = (int*)(p + o);         o = align_up(o + (size_t)NN * 4, 512);
    int* cursor = (int*)(p + o);      o = align_up(o + (size_t)NN * 4, 512);
    int* off = (int*)(p + o);         o = align_up(o + (size_t)(NN + 1) * 4, 512);
    int* bsums = (int*)(p + o);       o = align_up(o + 512, 512);
    int2* csr = (int2*)(p + o);       o = align_up(o + (size_t)NE * 8, 512);
    unsigned short* whi = (unsigned short*)(p + o); o = align_up(o + (size_t)NL * 16384 * 2, 512);
    unsigned short* wlo = (unsigned short*)(p + o); o = align_up(o + (size_t)NL * 16384 * 2, 512);
    (void)ws_size; (void)in_sizes; (void)n_in; (void)out_size;

    const int GRID_E = (NE + 255) / 256;          // 1563
    const int GRID_SCAN1 = (NN + 1023) / 1024;    // 98
    const int GRID_N256 = (NN + 255) / 256;       // 391
    const int GRID_EXP = NN / 2;                  // 50000
    const int GRID_AGG = NN / 8;                  // 12500
    const int GRID_GEMM = GROWS / 128;            // 782
    const int GRID_POOL = (NN + 63) / 64;         // 1563
    const int GRID_WPACK = NL * 16384 / 256;      // 320

    // zero deg + cursor (ws is poisoned 0xAA each call)
    hipMemsetAsync(deg, 0, (size_t)NN * 4, stream);
    hipMemsetAsync(cursor, 0, (size_t)NN * 4, stream);
    hipMemsetAsync(out, 0, (size_t)NG * DD * 4, stream);

    deg_kernel<<<GRID_E, 256, 0, stream>>>(ei, deg);
    scan1_kernel<<<GRID_SCAN1, 256, 0, stream>>>(deg, off, bsums);
    scan2_kernel<<<1, 128, 0, stream>>>(bsums, GRID_SCAN1);
    finish_kernel<<<GRID_N256, 256, 0, stream>>>(off, bsums, deg, dinv);
    fill_kernel<<<GRID_E, 256, 0, stream>>>(ei, off, cursor, csr, dinv);
    wpack_kernel<<<GRID_WPACK, 256, 0, stream>>>(Wg, whi, wlo);

    expand_kernel<<<GRID_EXP, 256, 0, stream>>>(x, We, be, h);

    for (int l = 0; l < NL; ++l) {
        agg_kernel<<<GRID_AGG, 256, 0, stream>>>(h, g, off, csr, dinv);
        mfma_gemm<<<GRID_GEMM, 256, 0, stream>>>(g, h,
                                                 whi + (size_t)l * 16384,
                                                 wlo + (size_t)l * 16384,
                                                 bg + (size_t)l * DD);
    }

    pool_kernel<<<GRID_POOL, 128, 0, stream>>>(h, bat, out);
}